// Round 14
// baseline (219.703 us; speedup 1.0000x reference)
//
#include <hip/hip_runtime.h>
#include <hip/hip_cooperative_groups.h>
#include <cstdint>
#include <cstddef>

namespace cg = cooperative_groups;

// FeatureAttention: x[4,2048,1024] fp32; Q=xWq^T+bq, K=xWk^T+bk, V=xWv^T+bv;
// out = softmax(QK^T/32) V.  bf16 MFMA pipeline.
//
// R18: bilinear factorization. S = QK^T = X M X^T + a 1^T + 1 b^T with
//   M = Wq^T Wk, a = X(Wq^T bk) + (bq.bk), b = X(Wk^T bq).
// Q/K are never materialized: proj (1024 units) -> G1 = X Mt^T (512) +
// Mt (64, via transposed weights) + tiny vector units. -448 GEMM units.
// Single coop kernel, 512 blocks, ONE grid.sync (cast->rest); everything
// else ordered by R16/R17-proven release/acquire panel counters.
//   phase0: v1/v2 (8u) | x-cast (4096u) | Wv-cast (512u) | WqT,WkT (128u)
//   phase1: Mt (64u) | av,bv (128u) | Vt (512u) | G1 (512u, spins mtc)
//   phase2: Sc = exp((G1 X^T + a[m] + b[n])/32)  (1024u, spins g1c/avc/bvc)
//   phase3: out = Sc Vt^T / rowsum  (512u, spins scc/vtc)
// Fallback (no coop / small ws): R14 4-dispatch non-factorized path.
//
// ws layout (MB): Xb[0,16) Wvb[20,22) G1[32,48) WqT[48,50) WkT[50,52)
//   Mt[52,54) avv@54 bvv@54+64K v1@54+128K v2@54+132K cnt@56 Vt[64,80)
//   Sc[80,112)

typedef unsigned short ushort_t;
typedef __attribute__((ext_vector_type(8))) short short8;
typedef __attribute__((ext_vector_type(4))) float f32x4;

#define AS1 __attribute__((address_space(1)))
#define AS3 __attribute__((address_space(3)))

__device__ __forceinline__ ushort_t f2bf(float f) {
    unsigned int u = __float_as_uint(f);
    u += 0x7FFFu + ((u >> 16) & 1u);
    return (ushort_t)(u >> 16);
}

__device__ __forceinline__ void async_ld16(const void* g, unsigned lds_off) {
    __builtin_amdgcn_global_load_lds((const AS1 void*)(uintptr_t)g,
                                     (AS3 void*)(uintptr_t)lds_off,
                                     16, 0, 0);
}

// panel dataflow (R16/R17-proven)
__device__ __forceinline__ void panel_arrive(int* c) {
    __syncthreads();
    if (threadIdx.x == 0)
        __hip_atomic_fetch_add(c, 1, __ATOMIC_RELEASE,
                               __HIP_MEMORY_SCOPE_AGENT);
}
__device__ __forceinline__ void spin1(int* c, int tgt) {
    while (__hip_atomic_load(c, __ATOMIC_ACQUIRE,
                             __HIP_MEMORY_SCOPE_AGENT) < tgt)
        __builtin_amdgcn_s_sleep(8);
}

template <int GX, int GY, int GZ, int CX, int CY>
__device__ __forceinline__ void remapC(int id, int& bx, int& by, int& bz) {
    constexpr int CZ  = (GX * GY * GZ) / (8 * CX * CY);
    constexpr int NCX = GX / CX, NCY = GY / CY;
    const int xcd = id & 7, jj = id >> 3;
    const int cx = xcd % NCX, ct = xcd / NCX;
    const int cy = ct % NCY, cz = ct / NCY;
    bx = cx * CX + (jj % CX);
    by = cy * CY + ((jj / CX) % CY);
    bz = cz * CZ + jj / (CX * CY);
}

// ---------------------------------------------------------------------------
// gemm_unit: 128x128 tile, BK=64 issue-early dbuf, 4 waves 2x2 (proven).
// EPI: 0 none | 1 +bias(n) split1024 | 2 +b0[m] | 3 exp(v)
//      4 v/rowsum(A) (ones-MFMA) | 5 exp((v + b0[m] + b1[n]) * scale)
// ---------------------------------------------------------------------------
template <typename OT, int EPI>
__device__ __forceinline__ void gemm_unit(
    ushort_t (&As)[2][8192], ushort_t (&Bs)[2][8192], float (&rs)[128],
    const ushort_t* __restrict__ A, const ushort_t* __restrict__ B,
    const float* __restrict__ b0, const float* __restrict__ b1,
    OT* __restrict__ C, int NT, int lda, int ldb, int ldc, float scale,
    int m0, int n0)
{
    constexpr int BK = 64;
    const int tid  = threadIdx.x;
    const int wave = tid >> 6;
    const int lane = tid & 63;
    const int wm = (wave >> 1) * 64;
    const int wn = (wave & 1) * 64;

    const unsigned lw  = (unsigned)(wave << 10);
    const unsigned aL0 = (unsigned)(uintptr_t)&As[0][0] + lw;
    const unsigned aL1 = (unsigned)(uintptr_t)&As[1][0] + lw;
    const unsigned bL0 = (unsigned)(uintptr_t)&Bs[0][0] + lw;
    const unsigned bL1 = (unsigned)(uintptr_t)&Bs[1][0] + lw;

    const int srow = wave * 8 + (lane >> 3);
    const int cd   = ((lane & 7) - srow) & 7;
    const ushort_t* gA = A + (size_t)(m0 + srow) * lda + cd * 8;
    const ushort_t* gB = B + (size_t)(n0 + srow) * ldb + cd * 8;

    auto stageT = [&](int t, unsigned la, unsigned lb) {
        const ushort_t* pA = gA + (size_t)t * BK;
        const ushort_t* pB = gB + (size_t)t * BK;
#pragma unroll
        for (int c = 0; c < 4; ++c) {
            async_ld16(pA + (size_t)(c * 32) * lda, la + c * 4096);
            async_ld16(pB + (size_t)(c * 32) * ldb, lb + c * 4096);
        }
    };

    const int frow = lane & 15;
    const int fg   = lane >> 4;

    f32x4 acc[4][4] = {};
    f32x4 rsm[4] = {};
    const short8 ones = { (short)0x3F80, (short)0x3F80, (short)0x3F80,
                          (short)0x3F80, (short)0x3F80, (short)0x3F80,
                          (short)0x3F80, (short)0x3F80 };

    auto computeT = [&](const ushort_t* Aw, const ushort_t* Bw) {
#pragma unroll
        for (int t2 = 0; t2 < 2; ++t2) {
            const int pa = (((t2 << 2) + fg + frow) & 7) << 3;
            short8 af[4], bf[4];
#pragma unroll
            for (int i = 0; i < 4; ++i)
                af[i] = *(const short8*)&Aw[(wm + i * 16 + frow) * BK + pa];
            if (EPI == 4 && wn == 0) {
#pragma unroll
                for (int i = 0; i < 4; ++i)
                    rsm[i] = __builtin_amdgcn_mfma_f32_16x16x32_bf16(
                        af[i], ones, rsm[i], 0, 0, 0);
            }
#pragma unroll
            for (int j = 0; j < 4; ++j)
                bf[j] = *(const short8*)&Bw[(wn + j * 16 + frow) * BK + pa];
#pragma unroll
            for (int i = 0; i < 4; ++i)
#pragma unroll
                for (int j = 0; j < 4; ++j)
                    acc[i][j] = __builtin_amdgcn_mfma_f32_16x16x32_bf16(
                        af[i], bf[j], acc[i][j], 0, 0, 0);
        }
    };

    const ushort_t* A0 = &As[0][0];
    const ushort_t* A1 = &As[1][0];
    const ushort_t* B0 = &Bs[0][0];
    const ushort_t* B1 = &Bs[1][0];

    stageT(0, aL0, bL0);
    __syncthreads();

    int t = 0;
    for (; t + 2 < NT; t += 2) {
        stageT(t + 1, aL1, bL1);
        computeT(A0, B0);
        __syncthreads();
        stageT(t + 2, aL0, bL0);
        computeT(A1, B1);
        __syncthreads();
    }
    stageT(NT - 1, aL1, bL1);
    computeT(A0, B0);
    __syncthreads();
    computeT(A1, B1);

    const int r0 = fg << 2;
    const int c0 = lane & 15;

    if (EPI == 4) {
        if (wn == 0 && c0 == 0) {
#pragma unroll
            for (int i = 0; i < 4; ++i)
#pragma unroll
                for (int r = 0; r < 4; ++r)
                    rs[wm + i * 16 + r0 + r] = rsm[i][r];
        }
        __syncthreads();
    }

    // C/D layout: lane l reg r -> row (l>>4)*4+r, col l&15
#pragma unroll
    for (int i = 0; i < 4; ++i) {
        float bm[4];
        if (EPI == 2 || EPI == 5) {
#pragma unroll
            for (int r = 0; r < 4; ++r)
                bm[r] = b0[m0 + wm + i * 16 + r0 + r];
        }
        if (EPI == 4) {
#pragma unroll
            for (int r = 0; r < 4; ++r)
                bm[r] = 1.0f / rs[wm + i * 16 + r0 + r];
        }
#pragma unroll
        for (int j = 0; j < 4; ++j) {
            const int n = n0 + wn + j * 16 + c0;
            float bn = 0.f;
            if (EPI == 1) bn = (n < 1024) ? b0[n] : b1[n - 1024];
            if (EPI == 5) bn = b1[n];
#pragma unroll
            for (int r = 0; r < 4; ++r) {
                const int m = m0 + wm + i * 16 + r0 + r;
                float v = acc[i][j][r];
                if (EPI == 5) {
                    v = __expf((v + bm[r] + bn) * scale);
                } else {
                    v *= scale;
                    if (EPI == 1) v += bn;
                    if (EPI == 2) v += bm[r];
                    if (EPI == 3) v = __expf(v);
                    if (EPI == 4) v *= bm[r];
                }
                if constexpr (sizeof(OT) == 2)
                    C[(size_t)m * ldc + n] = f2bf(v);
                else
                    C[(size_t)m * ldc + n] = v;
            }
        }
    }
}

// cast 2048 fp32 -> bf16
__device__ __forceinline__ void cast2048(const float* src, ushort_t* dst,
                                         size_t base) {
    const size_t i = base + threadIdx.x * 8;
    const f32x4 a = *(const f32x4*)(src + i);
    const f32x4 c = *(const f32x4*)(src + i + 4);
    short8 o;
    o[0] = (short)f2bf(a[0]); o[1] = (short)f2bf(a[1]);
    o[2] = (short)f2bf(a[2]); o[3] = (short)f2bf(a[3]);
    o[4] = (short)f2bf(c[0]); o[5] = (short)f2bf(c[1]);
    o[6] = (short)f2bf(c[2]); o[7] = (short)f2bf(c[3]);
    *(short8*)(dst + i) = o;
}

// 128x128 tile transpose: WT[d][u] = W[u][d], bf16 out, rotate-swizzled LDS
__device__ __forceinline__ void transpose_unit(int t, const float* W,
                                               ushort_t* WT, ushort_t* lds) {
    const int ti = t & 7, tj = t >> 3;
#pragma unroll 4
    for (int k = 0; k < 64; ++k) {
        const int idx = threadIdx.x + k * 256;
        const int r = idx >> 7, c = idx & 127;
        lds[r * 128 + ((c + r) & 127)] =
            f2bf(W[(size_t)(tj * 128 + r) * 1024 + ti * 128 + c]);
    }
    __syncthreads();
#pragma unroll 4
    for (int k = 0; k < 64; ++k) {
        const int idx = threadIdx.x + k * 256;
        const int rp = idx >> 7, cp = idx & 127;
        WT[(size_t)(ti * 128 + rp) * 1024 + tj * 128 + cp] =
            lds[cp * 128 + ((rp + cp) & 127)];
    }
    __syncthreads();
}

// v-units: t<4 -> v1[d] = sum_u Wq[u][d] bk[u];  t>=4 -> v2 from Wk,bq
__device__ __forceinline__ void v_unit(int t, const float* Wq, const float* Wk,
                                       const float* bq, const float* bk,
                                       float* v1, float* v2) {
    const int d = (t & 3) * 256 + threadIdx.x;
    const float* W = (t < 4) ? Wq : Wk;
    const float* b = (t < 4) ? bk : bq;
    float acc = 0.f;
    for (int u = 0; u < 1024; ++u)
        acc += W[(size_t)u * 1024 + d] * b[u];
    ((t < 4) ? v1 : v2)[d] = acc;
}

// av/bv unit: rows [t*128, t*128+128): out[r] = x_r . v  (+ bq.bk if isAv)
__device__ __forceinline__ void av_unit(int t, bool isAv, const float* x,
                                        const float* v, const float* bq,
                                        const float* bk, float* outv) {
    const int wave = threadIdx.x >> 6, lane = threadIdx.x & 63;
    float c = 0.f;
    if (isAv) {
#pragma unroll
        for (int k = 0; k < 16; ++k)
            c += bq[lane + 64 * k] * bk[lane + 64 * k];
        for (int s = 1; s < 64; s <<= 1) c += __shfl_xor(c, s, 64);
    }
    for (int rr = 0; rr < 32; ++rr) {
        const int row = t * 128 + wave * 32 + rr;
        const float* xr = x + (size_t)row * 1024;
        float a = 0.f;
#pragma unroll
        for (int e = 0; e < 4; ++e) {
            const f32x4 xv = *(const f32x4*)(xr + e * 256 + lane * 4);
            const f32x4 vv = *(const f32x4*)(v + e * 256 + lane * 4);
            a += xv[0] * vv[0] + xv[1] * vv[1] + xv[2] * vv[2] + xv[3] * vv[3];
        }
        for (int s = 1; s < 64; s <<= 1) a += __shfl_xor(a, s, 64);
        if (lane == 0) outv[row] = a + c;
    }
}

// ---------------------------------------------------------------------------
// mega: whole op, one cooperative kernel, one grid.sync.
// ---------------------------------------------------------------------------
__global__ __launch_bounds__(256, 2) void mega(
    const float* __restrict__ x,
    const float* __restrict__ Wq, const float* __restrict__ bq,
    const float* __restrict__ Wk, const float* __restrict__ bk,
    const float* __restrict__ Wv, const float* __restrict__ bv,
    float* __restrict__ out, char* __restrict__ ws)
{
    __shared__ __align__(16) ushort_t As[2][8192];
    __shared__ __align__(16) ushort_t Bs[2][8192];
    __shared__ float rs[128];

    const size_t MB = 1ull << 20;
    ushort_t* Xb  = (ushort_t*)(ws);
    ushort_t* Wvb = (ushort_t*)(ws + 20 * MB);
    ushort_t* G1  = (ushort_t*)(ws + 32 * MB);
    ushort_t* WqT = (ushort_t*)(ws + 48 * MB);
    ushort_t* WkT = (ushort_t*)(ws + 50 * MB);
    ushort_t* Mt  = (ushort_t*)(ws + 52 * MB);
    float*    avv = (float*)(ws + 54 * MB);
    float*    bvv = (float*)(ws + 54 * MB + 0x10000);
    float*    v1  = (float*)(ws + 54 * MB + 0x20000);
    float*    v2  = (float*)(ws + 54 * MB + 0x21000);
    int*      cnt = (int*)(ws + 56 * MB);
    int* mtc = cnt;        // 8   target 8
    int* avc = cnt + 8;    // 64  target 1
    int* bvc = cnt + 72;   // 64  target 1
    int* g1c = cnt + 136;  // 64  target 8
    int* vtc = cnt + 200;  // 32  target 16
    int* scc = cnt + 232;  // 64  target 16   (296 total)
    ushort_t* Vt = (ushort_t*)(ws + 64 * MB);
    ushort_t* Sc = (ushort_t*)(ws + 80 * MB);

    cg::grid_group grid = cg::this_grid();
    const int gb = blockIdx.x;
    const int GS = gridDim.x;

    // ---- phase 0: v1/v2 | x-cast | Wv-cast | transposes ----
    if (gb == 0 && threadIdx.x < 296) cnt[threadIdx.x] = 0;
    for (int u = gb; u < 4744; u += GS) {
        if (u < 8)          v_unit(u, Wq, Wk, bq, bk, v1, v2);
        else if (u < 4104)  cast2048(x,  Xb,  (size_t)(u - 8) * 2048);
        else if (u < 4616)  cast2048(Wv, Wvb, (size_t)(u - 4104) * 2048);
        else if (u < 4680)  transpose_unit(u - 4616, Wq, WqT, &Bs[0][0]);
        else                transpose_unit(u - 4680, Wk, WkT, &Bs[0][0]);
    }
    grid.sync();

    // ---- phase 1: Mt | av | bv | Vt | G1 ----
    for (int u = gb; u < 1216; u += GS) {
        if (u < 64) {                       // Mt[e][d] = sum_u WkT[e][.]WqT[d][.]
            const int mx = u & 7, my = u >> 3;
            gemm_unit<ushort_t, 0>(As, Bs, rs, WkT, WqT, nullptr, nullptr,
                                   Mt, 16, 1024, 1024, 1024, 1.0f,
                                   my * 128, mx * 128);
            panel_arrive(&mtc[my]);
        } else if (u < 128) {               // av
            av_unit(u - 64, true, x, v1, bq, bk, avv);
            panel_arrive(&avc[u - 64]);
        } else if (u < 192) {               // bv
            av_unit(u - 128, false, x, v2, bq, bk, bvv);
            panel_arrive(&bvc[u - 128]);
        } else if (u < 704) {               // Vt = Wv X^T + bv(row)
            int bx, by, bz;
            remapC<64, 8, 1, 16, 4>(u - 192, bx, by, bz);
            gemm_unit<ushort_t, 2>(As, Bs, rs, Wvb, Xb, bv, nullptr,
                                   Vt, 16, 1024, 1024, 8192, 1.0f,
                                   by * 128, bx * 128);
            panel_arrive(&vtc[by * 4 + (bx >> 4)]);
        } else {                            // G1 = X Mt^T  [8192x1024]
            int bx, by, bz;
            remapC<8, 64, 1, 4, 16>(u - 704, bx, by, bz);
            if (threadIdx.x == 0) spin1(&mtc[bx], 8);
            __syncthreads();
            gemm_unit<ushort_t, 0>(As, Bs, rs, Xb, Mt, nullptr, nullptr,
                                   G1, 16, 1024, 1024, 1024, 1.0f,
                                   by * 128, bx * 128);
            panel_arrive(&g1c[by]);
        }
    }

    // ---- phase 2: Sc = exp((G1 X^T + a[m] + b[n]) / 32), 2 units/block ----
#pragma unroll
    for (int q = 0; q < 2; ++q) {
        int sx, sy, sz;
        remapC<16, 16, 4, 8, 16>(gb + q * 512, sx, sy, sz);
        if (threadIdx.x == 0) {
            spin1(&g1c[sz * 16 + sy], 8);
            spin1(&avc[sz * 16 + sy], 1);
            spin1(&bvc[sz * 16 + sx], 1);
        }
        __syncthreads();
        const size_t xo = (size_t)sz * 2048 * 1024;
        gemm_unit<ushort_t, 5>(As, Bs, rs, G1 + xo, Xb + xo,
                               avv + sz * 2048, bvv + sz * 2048,
                               Sc + (size_t)sz * 2048 * 2048,
                               16, 1024, 1024, 2048, 0.03125f,
                               sy * 128, sx * 128);
        panel_arrive(&scc[sz * 16 + sy]);
    }

    // ---- phase 3: out = (Sc Vt^T) / rowsum ----
    {
        int bx, by, bz;
        remapC<8, 16, 4, 8, 8>(gb, bx, by, bz);
        if (threadIdx.x == 0) {
            spin1(&scc[bz * 16 + by], 16);
            spin1(&vtc[bx * 4 + bz], 16);
        }
        __syncthreads();
        gemm_unit<float, 4>(As, Bs, rs,
                            Sc + (size_t)bz * 2048 * 2048,
                            Vt + (size_t)bz * 2048,
                            nullptr, nullptr,
                            out + (size_t)bz * 2048 * 1024,
                            32, 2048, 8192, 1024, 1.0f,
                            by * 128, bx * 128);
    }
}

// ---------------------------------------------------------------------------
// Fallback path (R14, non-factorized): separate dispatches, proven.
// ---------------------------------------------------------------------------
template <typename OT, int EPI, int CX, int CY>
__global__ __launch_bounds__(256, 2) void gemm_db(
    const ushort_t* __restrict__ A, const ushort_t* __restrict__ B,
    OT* __restrict__ C, int NT, int lda, int ldb, int ldc, float scale,
    long long aOffZ, long long bOffZ, long long cOffZ)
{
    __shared__ __align__(16) ushort_t As[2][8192];
    __shared__ __align__(16) ushort_t Bs[2][8192];
    __shared__ float rs[128];

    const int GX  = gridDim.x, GY = gridDim.y, GZ = gridDim.z;
    const int bid = blockIdx.x + GX * (blockIdx.y + GY * blockIdx.z);
    const int xcd = bid & 7, jj = bid >> 3;
    const int CZ  = (GX * GY * GZ) / (8 * CX * CY);
    const int NCX = GX / CX, NCY = GY / CY;
    const int cx  = xcd % NCX, ct = xcd / NCX;
    const int cy  = ct % NCY, cz = ct / NCY;
    const int bx  = cx * CX + (jj % CX);
    const int by  = cy * CY + ((jj / CX) % CY);
    const int bz  = cz * CZ + jj / (CX * CY);

    gemm_unit<OT, EPI>(As, Bs, rs,
                       A + (size_t)bz * aOffZ, B + (size_t)bz * bOffZ,
                       nullptr, nullptr,
                       C + (size_t)bz * cOffZ, NT, lda, ldb, ldc, scale,
                       by * 128, bx * 128);
}

__global__ __launch_bounds__(256, 2) void gemm_mrg(
    const ushort_t* __restrict__ Xb, const ushort_t* __restrict__ Wqkb,
    const ushort_t* __restrict__ Wvb,
    const float* __restrict__ bq, const float* __restrict__ bk,
    const float* __restrict__ bv,
    ushort_t* __restrict__ QKb, ushort_t* __restrict__ Vtp)
{
    __shared__ __align__(16) ushort_t As[2][8192];
    __shared__ __align__(16) ushort_t Bs[2][8192];
    __shared__ float rs[128];

    int bx, by, bz;
    if (blockIdx.x < 1024) {
        remapC<16, 64, 1, 8, 16>((int)blockIdx.x, bx, by, bz);
        gemm_unit<ushort_t, 1>(As, Bs, rs, Xb, Wqkb, bq, bk,
                               QKb, 16, 1024, 1024, 2048, 1.0f,
                               by * 128, bx * 128);
    } else {
        remapC<64, 8, 1, 16, 4>((int)blockIdx.x - 1024, bx, by, bz);
        gemm_unit<ushort_t, 2>(As, Bs, rs, Wvb, Xb, bv, nullptr,
                               Vtp, 16, 1024, 1024, 8192, 1.0f,
                               by * 128, bx * 128);
    }
}

__global__ __launch_bounds__(256) void cvt_all(
    const float* __restrict__ x,  const float* __restrict__ wq,
    const float* __restrict__ wk, const float* __restrict__ wv,
    ushort_t* __restrict__ xb,  ushort_t* __restrict__ wqb,
    ushort_t* __restrict__ wkb, ushort_t* __restrict__ wvb)
{
    const int b = blockIdx.x;
    if (b < 4096)      cast2048(x,  xb,  (size_t)b * 2048);
    else if (b < 4608) cast2048(wq, wqb, (size_t)(b - 4096) * 2048);
    else if (b < 5120) cast2048(wk, wkb, (size_t)(b - 4608) * 2048);
    else               cast2048(wv, wvb, (size_t)(b - 5120) * 2048);
}

extern "C" void kernel_launch(void* const* d_in, const int* in_sizes, int n_in,
                              void* d_out, int out_size, void* d_ws, size_t ws_size,
                              hipStream_t stream)
{
    const float* x  = (const float*)d_in[0];
    const float* Wq = (const float*)d_in[1];
    const float* bq = (const float*)d_in[2];
    const float* Wk = (const float*)d_in[3];
    const float* bk = (const float*)d_in[4];
    const float* Wv = (const float*)d_in[5];
    const float* bv = (const float*)d_in[6];
    float* out = (float*)d_out;
    char* ws = (char*)d_ws;

    if (ws_size >= (128ull << 20)) {
        int nb = 0;
        hipError_t qe = hipOccupancyMaxActiveBlocksPerMultiprocessor(
            &nb, reinterpret_cast<const void*>(mega), 256, 0);
        if (qe == hipSuccess && nb >= 2) {
            void* args[] = { (void*)&x, (void*)&Wq, (void*)&bq, (void*)&Wk,
                             (void*)&bk, (void*)&Wv, (void*)&bv, (void*)&out,
                             (void*)&ws };
            hipError_t le = hipLaunchCooperativeKernel(
                reinterpret_cast<const void*>(mega), dim3(512), dim3(256),
                args, 0, stream);
            if (le == hipSuccess) return;
        }
    }

    // fallback: R14 4-dispatch path (non-factorized, proven)
    const size_t MB = 1ull << 20;
    ushort_t* Xb   = (ushort_t*)(ws);
    ushort_t* Wqkb = (ushort_t*)(ws + 16 * MB);
    ushort_t* Wvb  = (ushort_t*)(ws + 20 * MB);
    ushort_t* QKb  = (ushort_t*)(ws + 32 * MB);
    ushort_t* Vt   = (ushort_t*)(ws + 64 * MB);
    ushort_t* Sc   = (ushort_t*)(ws);

    cvt_all<<<dim3(5632), dim3(256), 0, stream>>>(
        x, Wq, Wk, Wv, Xb, Wqkb, (ushort_t*)(ws + 18 * MB), Wvb);

    gemm_mrg<<<dim3(1536), dim3(256), 0, stream>>>(
        Xb, Wqkb, Wvb, bq, bk, bv, QKb, Vt);

    gemm_db<ushort_t, 3, 8, 16><<<dim3(16, 16, 4), dim3(256), 0, stream>>>(
        QKb, QKb + 1024, Sc, 16, 2048, 2048, 2048,
        0.03125f, 2048ll * 2048, 2048ll * 2048, 2048ll * 2048);

    gemm_db<float, 4, 8, 8><<<dim3(8, 16, 4), dim3(256), 0, stream>>>(
        Sc, Vt, out, 32, 2048, 8192, 1024, 1.0f,
        2048ll * 2048, 2048ll, 2048ll * 1024);
}